// Round 18
// baseline (1456.731 us; speedup 1.0000x reference)
//
#include <hip/hip_runtime.h>

#define IMH 64
#define IMW 64
#define HWSZ 4096
#define BATCH 16
#define TSTEPS 16
#define PADW 66

typedef _Float16 half8 __attribute__((ext_vector_type(8)));
typedef _Float16 half4 __attribute__((ext_vector_type(4)));
typedef float floatx4 __attribute__((ext_vector_type(4)));
typedef int intx4 __attribute__((ext_vector_type(4)));

__device__ __forceinline__ float sigmoidf_(float x) { return 1.f / (1.f + __expf(-x)); }
__device__ __forceinline__ float tanhf_(float x) { return 1.f - 2.f / (1.f + __expf(2.f * x)); }

// layer1 weights: 36 slabs wr[gt][m][k32]; m=(g*4+hg)*16+i -> out=g*64+hg*16+i; ci=chunk*32+k.
__global__ void repack_w1(const float* __restrict__ w, _Float16* __restrict__ wr) {
    int total = 36 * 8192;
    for (int idx = blockIdx.x * blockDim.x + threadIdx.x; idx < total;
         idx += gridDim.x * blockDim.x) {
        int k = idx & 31;
        int m = (idx >> 5) & 255;
        int gt = idx >> 13;
        int chunk = gt / 9, tap = gt - chunk * 9;
        int g = m >> 6, hg = (m >> 4) & 3, i = m & 15;
        int out = g * 64 + hg * 16 + i;
        int ci = chunk * 32 + k;
        wr[idx] = (_Float16)w[(out * 128 + ci) * 9 + tap];
    }
}

// layer0 weights: 18 h-slabs (ci = chunk*32+k+1) + 1 x-slab (K-dim = tap: A[m][k]=w_x[out][k], k<9).
__global__ void repack_w0(const float* __restrict__ w, _Float16* __restrict__ wr) {
    int total = 19 * 8192;
    for (int idx = blockIdx.x * blockDim.x + threadIdx.x; idx < total;
         idx += gridDim.x * blockDim.x) {
        int k = idx & 31;
        int m = (idx >> 5) & 255;
        int gt = idx >> 13;
        int g = m >> 6, hg = (m >> 4) & 3, i = m & 15;
        int out = g * 64 + hg * 16 + i;
        float v = 0.f;
        if (gt < 18) {
            int chunk = gt / 9, tap = gt - chunk * 9;
            v = w[(out * 65 + (chunk * 32 + k + 1)) * 9 + tap];
        } else if (k < 9) {
            v = w[(out * 65 + 0) * 9 + k];   // x-plane, tap k
        }
        wr[idx] = (_Float16)v;
    }
}

// zero ONLY the halo border ring of the 4 contiguous h buffers.
__global__ void border_zero(_Float16* hp) {
    const int total = 4 * BATCH * 260 * 16;          // units of half4
    int idx = blockIdx.x * blockDim.x + threadIdx.x;
    if (idx >= total) return;
    int u = idx & 15;
    int t = idx >> 4;
    int e = t % 260; t /= 260;
    int b = t & 15;
    int buf = t >> 4;
    int py, px;
    if (e < 66)       { py = 0;       px = e; }
    else if (e < 132) { py = 65;      px = e - 66; }
    else if (e < 196) { py = e - 131; px = 0; }
    else              { py = e - 195; px = 65; }
    _Float16* p = hp + (size_t)buf * (BATCH * PADW * PADW * 64)
                + (((b * PADW + py) * PADW + px) << 6) + u * 4;
    *(half4*)p = (half4){(_Float16)0.f, (_Float16)0.f, (_Float16)0.f, (_Float16)0.f};
}

// ---- champion block structure: 256 thr = 4 waves = 4 hid-groups,
// ---- ONE image row x 64 cols, wave tile M=64 x N=64.
// ---- R18: __launch_bounds__(256,2) — ~256-reg/wave budget for 2-3 taps of
// ---- fragment prefetch in flight. R17 showed realized occupancy is ~8.9
// ---- waves/CU regardless; only the compiler budget changes.

__device__ __forceinline__ void stage_h(const _Float16* __restrict__ buf, int halfsel,
                                        _Float16* __restrict__ act, int tid, int b, int rb) {
    const int rowbase = (b * PADW + rb) * PADW;
    for (int t = tid; t < 792; t += 256) {
        int pix = t >> 2, sl = t & 3;
        int r = pix / 66, cs = pix - r * 66;
        int gofs = ((rowbase + r * PADW + cs) << 6) + (halfsel << 5) + (sl << 3);
        *(intx4*)&act[(pix * 5 + sl) * 8] = *(const intx4*)(buf + gofs);
    }
}

// NH = # of 32-ch h chunks; XS = append x-slab (taps in K-dim, staged in extra at
// kernel start — chunk-loop barriers order it); CLOAD = load previous c;
// HEAD = fuse 1x1-conv+ReLU head, skip h/c stores (final dispatch only).
template<int NH, bool XS, bool CLOAD, bool HEAD>
__device__ __forceinline__ void lstm_body(
    const _Float16* __restrict__ srcA,    // h chunks 0-1
    const _Float16* __restrict__ srcB,    // h chunks 2-3
    const float* __restrict__ xsrc,       // layer0 x_t
    _Float16* __restrict__ hpad,          // out h [B][66][66][64]
    float* __restrict__ cpix,             // in-place c [B][4096][64]
    const _Float16* __restrict__ wr,      // [NH*9(+1)][256][32]
    const float* __restrict__ bias,       // [256]
    const float* __restrict__ wh,         // [64]  (HEAD)
    const float* __restrict__ bh,         // [1]   (HEAD)
    float* __restrict__ outp,             // [B][64][64] (HEAD)
    _Float16* __restrict__ act,           // LDS, 198*5*8 halves
    _Float16* __restrict__ extra,         // LDS, 5120 halves: x-slab (XS) / head scratch
    int tid, int rb, int b)
{
    const int lane = tid & 63;
    const int n = lane & 15, q = lane >> 4;
    const int hg = tid >> 6;

    if (XS) {
        // x-slab staging at block start: B[k=tap][col], col=pix, k=sl*8+j (k>=9 zero)
        int pix = tid >> 2, sl = tid & 3;
        half8 hv;
        #pragma unroll
        for (int j = 0; j < 8; ++j) hv[j] = (_Float16)0.f;
        const float* xb = xsrc + b * (TSTEPS * HWSZ);
        if (sl == 0) {
            #pragma unroll
            for (int j = 0; j < 8; ++j) {
                int gy = rb - 1 + j / 3, gx = pix - 1 + j % 3;
                if (gy >= 0 && gy < IMH && gx >= 0 && gx < IMW)
                    hv[j] = (_Float16)xb[gy * IMW + gx];
            }
        } else if (sl == 1) {
            int gy = rb + 1, gx = pix + 1;               // tap 8: dy=2,dx=2
            if (gy < IMH && gx < IMW)
                hv[0] = (_Float16)xb[gy * IMW + gx];
        }
        *(half8*)&extra[(pix * 5 + sl) * 8] = hv;
    }

    floatx4 acc[4][4];
    #pragma unroll
    for (int g = 0; g < 4; ++g)
        #pragma unroll
        for (int i = 0; i < 4; ++i) acc[g][i] = (floatx4){0.f, 0.f, 0.f, 0.f};

    #pragma unroll
    for (int chunk = 0; chunk < NH; ++chunk) {
        __syncthreads();                     // prev act readers done (orders extra too)
        stage_h((chunk < 2) ? srcA : srcB, chunk & 1, act, tid, b, rb);
        __syncthreads();                     // writes visible
        const _Float16* wbase = wr + (chunk * 9) * 8192 + (hg * 16 + n) * 32 + q * 8;
        #pragma unroll
        for (int tap = 0; tap < 9; ++tap) {
            half8 wfr[4];
            #pragma unroll
            for (int g = 0; g < 4; ++g)
                wfr[g] = *(const half8*)(wbase + tap * 8192 + g * 2048);
            const int dy = tap / 3, dx = tap - dy * 3;
            half8 bfr[4];
            #pragma unroll
            for (int ni = 0; ni < 4; ++ni) {
                int col = 16 * ni + n + dx;
                bfr[ni] = *(const half8*)&act[((dy * 66 + col) * 5 + q) * 8];
            }
            #pragma unroll
            for (int g = 0; g < 4; ++g)
                #pragma unroll
                for (int ni = 0; ni < 4; ++ni)
                    acc[g][ni] = __builtin_amdgcn_mfma_f32_16x16x32_f16(
                        wfr[g], bfr[ni], acc[g][ni], 0, 0, 0);
        }
    }

    if (XS) {
        if (NH == 0) __syncthreads();        // only barrier needed when no chunks ran
        const _Float16* wbase = wr + (NH * 9) * 8192 + (hg * 16 + n) * 32 + q * 8;
        half8 wfr[4];
        #pragma unroll
        for (int g = 0; g < 4; ++g)
            wfr[g] = *(const half8*)(wbase + g * 2048);
        half8 bfr[4];
        #pragma unroll
        for (int ni = 0; ni < 4; ++ni)
            bfr[ni] = *(const half8*)&extra[((16 * ni + n) * 5 + q) * 8];
        #pragma unroll
        for (int g = 0; g < 4; ++g)
            #pragma unroll
            for (int ni = 0; ni < 4; ++ni)
                acc[g][ni] = __builtin_amdgcn_mfma_f32_16x16x32_f16(
                    wfr[g], bfr[ni], acc[g][ni], 0, 0, 0);
    }

    // Epilogue: lane holds gates for h = hg*16+q*4+r, pixel row rb, col 16*ni+n
    const int hb = hg * 16 + q * 4;
    floatx4 bi = *(const floatx4*)&bias[hb];
    floatx4 bf = *(const floatx4*)&bias[64 + hb];
    floatx4 bo = *(const floatx4*)&bias[128 + hb];
    floatx4 bg = *(const floatx4*)&bias[192 + hb];
    float* hd = (float*)extra;               // HEAD scratch: [64 col][17]
    float whv[4];
    if (HEAD) {
        #pragma unroll
        for (int r = 0; r < 4; ++r) whv[r] = wh[hb + r];
    }
    #pragma unroll
    for (int ni = 0; ni < 4; ++ni) {
        int col = 16 * ni + n;
        int cidx = ((b * HWSZ + rb * IMW + col) << 6) + hb;      // 32-bit offset
        floatx4 cold;
        if (CLOAD) cold = *(const floatx4*)(cpix + cidx);
        else       cold = (floatx4){0.f, 0.f, 0.f, 0.f};
        floatx4 cnew;
        half4 hv;
        #pragma unroll
        for (int r = 0; r < 4; ++r) {
            float zi = acc[0][ni][r] + bi[r];
            float zf = acc[1][ni][r] + bf[r];
            float zo = acc[2][ni][r] + bo[r];
            float zg = acc[3][ni][r] + bg[r];
            float cn = CLOAD ? fmaf(sigmoidf_(zf), cold[r], sigmoidf_(zi) * tanhf_(zg))
                             : sigmoidf_(zi) * tanhf_(zg);
            cnew[r] = cn;
            hv[r] = (_Float16)(sigmoidf_(zo) * tanhf_(cn));
        }
        if (HEAD) {
            // partial head sum over this lane's 4 hids (f16-rounded h, same numerics)
            float p = 0.f;
            #pragma unroll
            for (int r = 0; r < 4; ++r) p = fmaf((float)hv[r], whv[r], p);
            hd[col * 17 + (hg * 4 + q)] = p;
        } else {
            *(floatx4*)(cpix + cidx) = cnew;
            int hidx = (((b * PADW + rb + 1) * PADW + col + 1) << 6) + hb;
            *(half4*)(hpad + hidx) = hv;
        }
    }
    if (HEAD) {
        __syncthreads();
        if (tid < 64) {
            float s = bh[0];
            #pragma unroll
            for (int j = 0; j < 16; ++j) s += hd[tid * 17 + j];
            outp[b * HWSZ + rb * IMW + tid] = fmaxf(s, 0.f);
        }
    }
}

// ZMODE: 0 = role0 (L1) only, 1 = role1 (L0) only, 2 = both via blockIdx.z.
template<int NH1, bool C1, bool HEAD1, int NH0, bool XS0, bool C0, int ZMODE>
__global__ __launch_bounds__(256, 2) void fused_step(
    const _Float16* __restrict__ a1, const _Float16* __restrict__ b1,
    _Float16* __restrict__ h1o, float* __restrict__ c1p,
    const _Float16* __restrict__ w1r, const float* __restrict__ bias1,
    const _Float16* __restrict__ a0, const float* __restrict__ x0,
    _Float16* __restrict__ h0o, float* __restrict__ c0p,
    const _Float16* __restrict__ w0r, const float* __restrict__ bias0,
    const float* __restrict__ wh, const float* __restrict__ bh,
    float* __restrict__ outp)
{
    __shared__ __align__(16) _Float16 act[198 * 5 * 8];   // 15.8 KB
    __shared__ __align__(16) _Float16 extra[64 * 5 * 8];  // 10 KB: x-slab / head scratch
    const int tid = threadIdx.x;
    // XCD-aware row swizzle: under the id%8 XCD heuristic, one XCD handles a
    // contiguous 8-row band (all batches, both roles) -> halo + h0new + c rows
    // stay XCD-L2-local. Pure permutation: correctness-neutral.
    const int rb = ((blockIdx.x & 7) << 3) | (blockIdx.x >> 3);
    const int b = blockIdx.y;
    const int role = (ZMODE == 2) ? (int)blockIdx.z : ZMODE;
    if (ZMODE != 1 && role == 0)
        lstm_body<NH1, false, C1, HEAD1>(a1, b1, nullptr, h1o, c1p, w1r, bias1,
                                         wh, bh, outp, act, extra, tid, rb, b);
    else
        lstm_body<NH0, XS0, C0, false>(a0, nullptr, x0, h0o, c0p, w0r, bias0,
                                       nullptr, nullptr, nullptr, act, extra, tid, rb, b);
}

extern "C" void kernel_launch(void* const* d_in, const int* in_sizes, int n_in,
                              void* d_out, int out_size, void* d_ws, size_t ws_size,
                              hipStream_t stream) {
    const float* x  = (const float*)d_in[0];
    const float* w0 = (const float*)d_in[1];
    const float* b0 = (const float*)d_in[2];
    const float* w1 = (const float*)d_in[3];
    const float* b1 = (const float*)d_in[4];
    const float* wh = (const float*)d_in[5];
    const float* bh = (const float*)d_in[6];
    float* out = (float*)d_out;

    const size_t HPAD = (size_t)BATCH * PADW * PADW * 64;  // 4,460,544 halves
    const size_t CBUF = (size_t)BATCH * HWSZ * 64;         // 4,194,304 floats
    _Float16* hp  = (_Float16*)d_ws;
    _Float16* h0a = hp;
    _Float16* h0b = hp + HPAD;
    _Float16* h1a = hp + 2 * HPAD;
    _Float16* h1b = hp + 3 * HPAD;
    float* cbase = (float*)(hp + 4 * HPAD);
    float* c0 = cbase;
    float* c1 = cbase + CBUF;
    _Float16* wr0 = (_Float16*)(cbase + 2 * CBUF);   // 19*8192 halves
    _Float16* wr1 = wr0 + (size_t)19 * 8192;         // 36*8192 halves

    // Only h BORDERS need zeroing (interiors & c are written before read).
    border_zero<<<1040, 256, 0, stream>>>(hp);
    repack_w0<<<608, 256, 0, stream>>>(w0, wr0);
    repack_w1<<<1152, 256, 0, stream>>>(w1, wr1);

    _Float16* h0buf[2] = {h0a, h0b};
    _Float16* h1buf[2] = {h1a, h1b};
    dim3 block(256);

    // D0 = L0(0): h0(-1)=0 -> x-slab only (NH=0), c0(-1)=0 -> no c load.
    fused_step<0, false, false, 0, true, false, 1><<<dim3(64, BATCH, 1), block, 0, stream>>>(
        nullptr, nullptr, nullptr, nullptr, nullptr, nullptr,
        nullptr, x, h0buf[1], c0, wr0 + (size_t)18 * 8192, b0,
        nullptr, nullptr, nullptr);

    // D1 (t=1): role0 = L1(0): h1(-1)=0 -> NH=2, no c1 load; role1 = L0(1) full.
    fused_step<2, false, false, 2, true, true, 2><<<dim3(64, BATCH, 2), block, 0, stream>>>(
        h0buf[1], nullptr, h1buf[1], c1, wr1, b1,
        h0buf[1], x + (size_t)HWSZ, h0buf[0], c0, wr0, b0,
        nullptr, nullptr, nullptr);

    // steady t=2..15: role0 = L1(t-1) full; role1 = L0(t) full.
    for (int t = 2; t < TSTEPS; ++t) {
        fused_step<4, true, false, 2, true, true, 2><<<dim3(64, BATCH, 2), block, 0, stream>>>(
            h0buf[t & 1], h1buf[(t - 1) & 1], h1buf[t & 1], c1, wr1, b1,
            h0buf[t & 1], x + (size_t)t * HWSZ, h0buf[(t + 1) & 1], c0, wr0, b0,
            nullptr, nullptr, nullptr);
    }

    // final: L1(15) + fused head: writes ONLY the head output.
    fused_step<4, true, true, 0, false, false, 0><<<dim3(64, BATCH, 1), block, 0, stream>>>(
        h0buf[0], h1buf[1], nullptr, c1, wr1, b1,
        nullptr, nullptr, nullptr, nullptr, nullptr, nullptr,
        wh, bh, out);
}

// Round 19
// 1315.143 us; speedup vs baseline: 1.1077x; 1.1077x over previous
//
#include <hip/hip_runtime.h>

#define IMH 64
#define IMW 64
#define HWSZ 4096
#define BATCH 16
#define TSTEPS 16
#define PADW 66

typedef _Float16 half8 __attribute__((ext_vector_type(8)));
typedef _Float16 half4 __attribute__((ext_vector_type(4)));
typedef float floatx4 __attribute__((ext_vector_type(4)));
typedef int intx4 __attribute__((ext_vector_type(4)));

__device__ __forceinline__ float sigmoidf_(float x) { return 1.f / (1.f + __expf(-x)); }
__device__ __forceinline__ float tanhf_(float x) { return 1.f - 2.f / (1.f + __expf(2.f * x)); }

// layer1 weights: 36 slabs wr[gt][m][k32]; m=(g*4+hg)*16+i -> out=g*64+hg*16+i; ci=chunk*32+k.
__global__ void repack_w1(const float* __restrict__ w, _Float16* __restrict__ wr) {
    int total = 36 * 8192;
    for (int idx = blockIdx.x * blockDim.x + threadIdx.x; idx < total;
         idx += gridDim.x * blockDim.x) {
        int k = idx & 31;
        int m = (idx >> 5) & 255;
        int gt = idx >> 13;
        int chunk = gt / 9, tap = gt - chunk * 9;
        int g = m >> 6, hg = (m >> 4) & 3, i = m & 15;
        int out = g * 64 + hg * 16 + i;
        int ci = chunk * 32 + k;
        wr[idx] = (_Float16)w[(out * 128 + ci) * 9 + tap];
    }
}

// layer0 weights: 18 h-slabs (ci = chunk*32+k+1) + 1 x-slab (K-dim = tap: A[m][k]=w_x[out][k], k<9).
__global__ void repack_w0(const float* __restrict__ w, _Float16* __restrict__ wr) {
    int total = 19 * 8192;
    for (int idx = blockIdx.x * blockDim.x + threadIdx.x; idx < total;
         idx += gridDim.x * blockDim.x) {
        int k = idx & 31;
        int m = (idx >> 5) & 255;
        int gt = idx >> 13;
        int g = m >> 6, hg = (m >> 4) & 3, i = m & 15;
        int out = g * 64 + hg * 16 + i;
        float v = 0.f;
        if (gt < 18) {
            int chunk = gt / 9, tap = gt - chunk * 9;
            v = w[(out * 65 + (chunk * 32 + k + 1)) * 9 + tap];
        } else if (k < 9) {
            v = w[(out * 65 + 0) * 9 + k];   // x-plane, tap k
        }
        wr[idx] = (_Float16)v;
    }
}

// zero ONLY the halo border ring of the 4 contiguous h buffers.
__global__ void border_zero(_Float16* hp) {
    const int total = 4 * BATCH * 260 * 16;          // units of half4
    int idx = blockIdx.x * blockDim.x + threadIdx.x;
    if (idx >= total) return;
    int u = idx & 15;
    int t = idx >> 4;
    int e = t % 260; t /= 260;
    int b = t & 15;
    int buf = t >> 4;
    int py, px;
    if (e < 66)       { py = 0;       px = e; }
    else if (e < 132) { py = 65;      px = e - 66; }
    else if (e < 196) { py = e - 131; px = 0; }
    else              { py = e - 195; px = 65; }
    _Float16* p = hp + (size_t)buf * (BATCH * PADW * PADW * 64)
                + (((b * PADW + py) * PADW + px) << 6) + u * 4;
    *(half4*)p = (half4){(_Float16)0.f, (_Float16)0.f, (_Float16)0.f, (_Float16)0.f};
}

// ---- champion block structure: 256 thr = 4 waves = 4 hid-groups,
// ---- ONE image row x 64 cols, wave tile M=64 x N=64.
// ---- __launch_bounds__(256,3): swept optimum — (256,4)=1401us, (256,3)=1337us,
// ---- (256,2)=1457us. Compiler settles at 84 VGPR; higher budgets only cut
// ---- occupancy (R18), lower ones block its ~1-tap fragment pipelining (R16).

__device__ __forceinline__ void stage_h(const _Float16* __restrict__ buf, int halfsel,
                                        _Float16* __restrict__ act, int tid, int b, int rb) {
    const int rowbase = (b * PADW + rb) * PADW;
    for (int t = tid; t < 792; t += 256) {
        int pix = t >> 2, sl = t & 3;
        int r = pix / 66, cs = pix - r * 66;
        int gofs = ((rowbase + r * PADW + cs) << 6) + (halfsel << 5) + (sl << 3);
        *(intx4*)&act[(pix * 5 + sl) * 8] = *(const intx4*)(buf + gofs);
    }
}

// NH = # of 32-ch h chunks; XS = append x-slab (taps in K-dim, staged in extra at
// kernel start — chunk-loop barriers order it); CLOAD = load previous c;
// HEAD = fuse 1x1-conv+ReLU head, skip h/c stores (final dispatch only).
template<int NH, bool XS, bool CLOAD, bool HEAD>
__device__ __forceinline__ void lstm_body(
    const _Float16* __restrict__ srcA,    // h chunks 0-1
    const _Float16* __restrict__ srcB,    // h chunks 2-3
    const float* __restrict__ xsrc,       // layer0 x_t
    _Float16* __restrict__ hpad,          // out h [B][66][66][64]
    float* __restrict__ cpix,             // in-place c [B][4096][64]
    const _Float16* __restrict__ wr,      // [NH*9(+1)][256][32]
    const float* __restrict__ bias,       // [256]
    const float* __restrict__ wh,         // [64]  (HEAD)
    const float* __restrict__ bh,         // [1]   (HEAD)
    float* __restrict__ outp,             // [B][64][64] (HEAD)
    _Float16* __restrict__ act,           // LDS, 198*5*8 halves
    _Float16* __restrict__ extra,         // LDS, 5120 halves: x-slab (XS) / head scratch
    int tid, int rb, int b)
{
    const int lane = tid & 63;
    const int n = lane & 15, q = lane >> 4;
    const int hg = tid >> 6;

    if (XS) {
        // x-slab staging at block start: B[k=tap][col], col=pix, k=sl*8+j (k>=9 zero)
        int pix = tid >> 2, sl = tid & 3;
        half8 hv;
        #pragma unroll
        for (int j = 0; j < 8; ++j) hv[j] = (_Float16)0.f;
        const float* xb = xsrc + b * (TSTEPS * HWSZ);
        if (sl == 0) {
            #pragma unroll
            for (int j = 0; j < 8; ++j) {
                int gy = rb - 1 + j / 3, gx = pix - 1 + j % 3;
                if (gy >= 0 && gy < IMH && gx >= 0 && gx < IMW)
                    hv[j] = (_Float16)xb[gy * IMW + gx];
            }
        } else if (sl == 1) {
            int gy = rb + 1, gx = pix + 1;               // tap 8: dy=2,dx=2
            if (gy < IMH && gx < IMW)
                hv[0] = (_Float16)xb[gy * IMW + gx];
        }
        *(half8*)&extra[(pix * 5 + sl) * 8] = hv;
    }

    floatx4 acc[4][4];
    #pragma unroll
    for (int g = 0; g < 4; ++g)
        #pragma unroll
        for (int i = 0; i < 4; ++i) acc[g][i] = (floatx4){0.f, 0.f, 0.f, 0.f};

    #pragma unroll
    for (int chunk = 0; chunk < NH; ++chunk) {
        __syncthreads();                     // prev act readers done (orders extra too)
        stage_h((chunk < 2) ? srcA : srcB, chunk & 1, act, tid, b, rb);
        __syncthreads();                     // writes visible
        const _Float16* wbase = wr + (chunk * 9) * 8192 + (hg * 16 + n) * 32 + q * 8;
        #pragma unroll
        for (int tap = 0; tap < 9; ++tap) {
            half8 wfr[4];
            #pragma unroll
            for (int g = 0; g < 4; ++g)
                wfr[g] = *(const half8*)(wbase + tap * 8192 + g * 2048);
            const int dy = tap / 3, dx = tap - dy * 3;
            half8 bfr[4];
            #pragma unroll
            for (int ni = 0; ni < 4; ++ni) {
                int col = 16 * ni + n + dx;
                bfr[ni] = *(const half8*)&act[((dy * 66 + col) * 5 + q) * 8];
            }
            #pragma unroll
            for (int g = 0; g < 4; ++g)
                #pragma unroll
                for (int ni = 0; ni < 4; ++ni)
                    acc[g][ni] = __builtin_amdgcn_mfma_f32_16x16x32_f16(
                        wfr[g], bfr[ni], acc[g][ni], 0, 0, 0);
        }
    }

    if (XS) {
        if (NH == 0) __syncthreads();        // only barrier needed when no chunks ran
        const _Float16* wbase = wr + (NH * 9) * 8192 + (hg * 16 + n) * 32 + q * 8;
        half8 wfr[4];
        #pragma unroll
        for (int g = 0; g < 4; ++g)
            wfr[g] = *(const half8*)(wbase + g * 2048);
        half8 bfr[4];
        #pragma unroll
        for (int ni = 0; ni < 4; ++ni)
            bfr[ni] = *(const half8*)&extra[((16 * ni + n) * 5 + q) * 8];
        #pragma unroll
        for (int g = 0; g < 4; ++g)
            #pragma unroll
            for (int ni = 0; ni < 4; ++ni)
                acc[g][ni] = __builtin_amdgcn_mfma_f32_16x16x32_f16(
                    wfr[g], bfr[ni], acc[g][ni], 0, 0, 0);
    }

    // Epilogue: lane holds gates for h = hg*16+q*4+r, pixel row rb, col 16*ni+n
    const int hb = hg * 16 + q * 4;
    floatx4 bi = *(const floatx4*)&bias[hb];
    floatx4 bf = *(const floatx4*)&bias[64 + hb];
    floatx4 bo = *(const floatx4*)&bias[128 + hb];
    floatx4 bg = *(const floatx4*)&bias[192 + hb];
    float* hd = (float*)extra;               // HEAD scratch: [64 col][17]
    float whv[4];
    if (HEAD) {
        #pragma unroll
        for (int r = 0; r < 4; ++r) whv[r] = wh[hb + r];
    }
    #pragma unroll
    for (int ni = 0; ni < 4; ++ni) {
        int col = 16 * ni + n;
        int cidx = ((b * HWSZ + rb * IMW + col) << 6) + hb;      // 32-bit offset
        floatx4 cold;
        if (CLOAD) cold = *(const floatx4*)(cpix + cidx);
        else       cold = (floatx4){0.f, 0.f, 0.f, 0.f};
        floatx4 cnew;
        half4 hv;
        #pragma unroll
        for (int r = 0; r < 4; ++r) {
            float zi = acc[0][ni][r] + bi[r];
            float zf = acc[1][ni][r] + bf[r];
            float zo = acc[2][ni][r] + bo[r];
            float zg = acc[3][ni][r] + bg[r];
            float cn = CLOAD ? fmaf(sigmoidf_(zf), cold[r], sigmoidf_(zi) * tanhf_(zg))
                             : sigmoidf_(zi) * tanhf_(zg);
            cnew[r] = cn;
            hv[r] = (_Float16)(sigmoidf_(zo) * tanhf_(cn));
        }
        if (HEAD) {
            // partial head sum over this lane's 4 hids (f16-rounded h, same numerics)
            float p = 0.f;
            #pragma unroll
            for (int r = 0; r < 4; ++r) p = fmaf((float)hv[r], whv[r], p);
            hd[col * 17 + (hg * 4 + q)] = p;
        } else {
            *(floatx4*)(cpix + cidx) = cnew;
            int hidx = (((b * PADW + rb + 1) * PADW + col + 1) << 6) + hb;
            *(half4*)(hpad + hidx) = hv;
        }
    }
    if (HEAD) {
        __syncthreads();
        if (tid < 64) {
            float s = bh[0];
            #pragma unroll
            for (int j = 0; j < 16; ++j) s += hd[tid * 17 + j];
            outp[b * HWSZ + rb * IMW + tid] = fmaxf(s, 0.f);
        }
    }
}

// ZMODE: 0 = role0 (L1) only, 1 = role1 (L0) only, 2 = both via blockIdx.z.
template<int NH1, bool C1, bool HEAD1, int NH0, bool XS0, bool C0, int ZMODE>
__global__ __launch_bounds__(256, 3) void fused_step(
    const _Float16* __restrict__ a1, const _Float16* __restrict__ b1,
    _Float16* __restrict__ h1o, float* __restrict__ c1p,
    const _Float16* __restrict__ w1r, const float* __restrict__ bias1,
    const _Float16* __restrict__ a0, const float* __restrict__ x0,
    _Float16* __restrict__ h0o, float* __restrict__ c0p,
    const _Float16* __restrict__ w0r, const float* __restrict__ bias0,
    const float* __restrict__ wh, const float* __restrict__ bh,
    float* __restrict__ outp)
{
    __shared__ __align__(16) _Float16 act[198 * 5 * 8];   // 15.8 KB
    __shared__ __align__(16) _Float16 extra[64 * 5 * 8];  // 10 KB: x-slab / head scratch
    const int tid = threadIdx.x;
    // XCD-aware row swizzle: under the id%8 XCD heuristic, one XCD handles a
    // contiguous 8-row band (all batches, both roles) -> halo + h0new + c rows
    // stay XCD-L2-local. Pure permutation: correctness-neutral.
    const int rb = ((blockIdx.x & 7) << 3) | (blockIdx.x >> 3);
    const int b = blockIdx.y;
    const int role = (ZMODE == 2) ? (int)blockIdx.z : ZMODE;
    if (ZMODE != 1 && role == 0)
        lstm_body<NH1, false, C1, HEAD1>(a1, b1, nullptr, h1o, c1p, w1r, bias1,
                                         wh, bh, outp, act, extra, tid, rb, b);
    else
        lstm_body<NH0, XS0, C0, false>(a0, nullptr, x0, h0o, c0p, w0r, bias0,
                                       nullptr, nullptr, nullptr, act, extra, tid, rb, b);
}

extern "C" void kernel_launch(void* const* d_in, const int* in_sizes, int n_in,
                              void* d_out, int out_size, void* d_ws, size_t ws_size,
                              hipStream_t stream) {
    const float* x  = (const float*)d_in[0];
    const float* w0 = (const float*)d_in[1];
    const float* b0 = (const float*)d_in[2];
    const float* w1 = (const float*)d_in[3];
    const float* b1 = (const float*)d_in[4];
    const float* wh = (const float*)d_in[5];
    const float* bh = (const float*)d_in[6];
    float* out = (float*)d_out;

    const size_t HPAD = (size_t)BATCH * PADW * PADW * 64;  // 4,460,544 halves
    const size_t CBUF = (size_t)BATCH * HWSZ * 64;         // 4,194,304 floats
    _Float16* hp  = (_Float16*)d_ws;
    _Float16* h0a = hp;
    _Float16* h0b = hp + HPAD;
    _Float16* h1a = hp + 2 * HPAD;
    _Float16* h1b = hp + 3 * HPAD;
    float* cbase = (float*)(hp + 4 * HPAD);
    float* c0 = cbase;
    float* c1 = cbase + CBUF;
    _Float16* wr0 = (_Float16*)(cbase + 2 * CBUF);   // 19*8192 halves
    _Float16* wr1 = wr0 + (size_t)19 * 8192;         // 36*8192 halves

    // Only h BORDERS need zeroing (interiors & c are written before read).
    border_zero<<<1040, 256, 0, stream>>>(hp);
    repack_w0<<<608, 256, 0, stream>>>(w0, wr0);
    repack_w1<<<1152, 256, 0, stream>>>(w1, wr1);

    _Float16* h0buf[2] = {h0a, h0b};
    _Float16* h1buf[2] = {h1a, h1b};
    dim3 block(256);

    // D0 = L0(0): h0(-1)=0 -> x-slab only (NH=0), c0(-1)=0 -> no c load.
    fused_step<0, false, false, 0, true, false, 1><<<dim3(64, BATCH, 1), block, 0, stream>>>(
        nullptr, nullptr, nullptr, nullptr, nullptr, nullptr,
        nullptr, x, h0buf[1], c0, wr0 + (size_t)18 * 8192, b0,
        nullptr, nullptr, nullptr);

    // D1 (t=1): role0 = L1(0): h1(-1)=0 -> NH=2, no c1 load; role1 = L0(1) full.
    fused_step<2, false, false, 2, true, true, 2><<<dim3(64, BATCH, 2), block, 0, stream>>>(
        h0buf[1], nullptr, h1buf[1], c1, wr1, b1,
        h0buf[1], x + (size_t)HWSZ, h0buf[0], c0, wr0, b0,
        nullptr, nullptr, nullptr);

    // steady t=2..15: role0 = L1(t-1) full; role1 = L0(t) full.
    for (int t = 2; t < TSTEPS; ++t) {
        fused_step<4, true, false, 2, true, true, 2><<<dim3(64, BATCH, 2), block, 0, stream>>>(
            h0buf[t & 1], h1buf[(t - 1) & 1], h1buf[t & 1], c1, wr1, b1,
            h0buf[t & 1], x + (size_t)t * HWSZ, h0buf[(t + 1) & 1], c0, wr0, b0,
            nullptr, nullptr, nullptr);
    }

    // final: L1(15) + fused head: writes ONLY the head output.
    fused_step<4, true, true, 0, false, false, 0><<<dim3(64, BATCH, 1), block, 0, stream>>>(
        h0buf[0], h1buf[1], nullptr, c1, wr1, b1,
        nullptr, nullptr, nullptr, nullptr, nullptr, nullptr,
        wh, bh, out);
}

// Round 20
// 1302.225 us; speedup vs baseline: 1.1186x; 1.0099x over previous
//
#include <hip/hip_runtime.h>

#define IMH 64
#define IMW 64
#define HWSZ 4096
#define BATCH 16
#define TSTEPS 16
#define PADW 66
#define ABUF 7920   // 198 px * 5 slots * 8 halves = one act buffer

typedef _Float16 half8 __attribute__((ext_vector_type(8)));
typedef _Float16 half4 __attribute__((ext_vector_type(4)));
typedef float floatx4 __attribute__((ext_vector_type(4)));
typedef int intx4 __attribute__((ext_vector_type(4)));

__device__ __forceinline__ float sigmoidf_(float x) { return 1.f / (1.f + __expf(-x)); }
__device__ __forceinline__ float tanhf_(float x) { return 1.f - 2.f / (1.f + __expf(2.f * x)); }

// layer1 weights: 36 slabs wr[gt][m][k32]; m=(g*4+hg)*16+i -> out=g*64+hg*16+i; ci=chunk*32+k.
__global__ void repack_w1(const float* __restrict__ w, _Float16* __restrict__ wr) {
    int total = 36 * 8192;
    for (int idx = blockIdx.x * blockDim.x + threadIdx.x; idx < total;
         idx += gridDim.x * blockDim.x) {
        int k = idx & 31;
        int m = (idx >> 5) & 255;
        int gt = idx >> 13;
        int chunk = gt / 9, tap = gt - chunk * 9;
        int g = m >> 6, hg = (m >> 4) & 3, i = m & 15;
        int out = g * 64 + hg * 16 + i;
        int ci = chunk * 32 + k;
        wr[idx] = (_Float16)w[(out * 128 + ci) * 9 + tap];
    }
}

// layer0 weights: 18 h-slabs (ci = chunk*32+k+1) + 1 x-slab (K-dim = tap: A[m][k]=w_x[out][k], k<9).
__global__ void repack_w0(const float* __restrict__ w, _Float16* __restrict__ wr) {
    int total = 19 * 8192;
    for (int idx = blockIdx.x * blockDim.x + threadIdx.x; idx < total;
         idx += gridDim.x * blockDim.x) {
        int k = idx & 31;
        int m = (idx >> 5) & 255;
        int gt = idx >> 13;
        int g = m >> 6, hg = (m >> 4) & 3, i = m & 15;
        int out = g * 64 + hg * 16 + i;
        float v = 0.f;
        if (gt < 18) {
            int chunk = gt / 9, tap = gt - chunk * 9;
            v = w[(out * 65 + (chunk * 32 + k + 1)) * 9 + tap];
        } else if (k < 9) {
            v = w[(out * 65 + 0) * 9 + k];   // x-plane, tap k
        }
        wr[idx] = (_Float16)v;
    }
}

// zero ONLY the halo border ring of the 4 contiguous h buffers.
__global__ void border_zero(_Float16* hp) {
    const int total = 4 * BATCH * 260 * 16;          // units of half4
    int idx = blockIdx.x * blockDim.x + threadIdx.x;
    if (idx >= total) return;
    int u = idx & 15;
    int t = idx >> 4;
    int e = t % 260; t /= 260;
    int b = t & 15;
    int buf = t >> 4;
    int py, px;
    if (e < 66)       { py = 0;       px = e; }
    else if (e < 132) { py = 65;      px = e - 66; }
    else if (e < 196) { py = e - 131; px = 0; }
    else              { py = e - 195; px = 65; }
    _Float16* p = hp + (size_t)buf * (BATCH * PADW * PADW * 64)
                + (((b * PADW + py) * PADW + px) << 6) + u * 4;
    *(half4*)p = (half4){(_Float16)0.f, (_Float16)0.f, (_Float16)0.f, (_Float16)0.f};
}

// ---- champion block structure: 256 thr = 4 waves = 4 hid-groups,
// ---- ONE image row x 64 cols, wave tile M=64 x N=64, __launch_bounds__(256,3)
// ---- (swept optimum). R20: act DOUBLE-buffered -> stage(k+1) overlaps taps(k),
// ---- ONE barrier per chunk instead of two; plain load->ds_write (no manual pf,
// ---- no DMA) — synchronization is __syncthreads only.

__device__ __forceinline__ void stage_h(const _Float16* __restrict__ buf, int halfsel,
                                        _Float16* __restrict__ dst, int tid, int b, int rb) {
    const int rowbase = (b * PADW + rb) * PADW;
    for (int t = tid; t < 792; t += 256) {
        int pix = t >> 2, sl = t & 3;
        int r = pix / 66, cs = pix - r * 66;
        int gofs = ((rowbase + r * PADW + cs) << 6) + (halfsel << 5) + (sl << 3);
        *(intx4*)&dst[(pix * 5 + sl) * 8] = *(const intx4*)(buf + gofs);
    }
}

// NH = # of 32-ch h chunks; XS = append x-slab; CLOAD = load previous c;
// HEAD = fuse 1x1-conv+ReLU head, skip h/c stores (final dispatch only).
template<int NH, bool XS, bool CLOAD, bool HEAD>
__device__ __forceinline__ void lstm_body(
    const _Float16* __restrict__ srcA,    // h chunks 0-1
    const _Float16* __restrict__ srcB,    // h chunks 2-3
    const float* __restrict__ xsrc,       // layer0 x_t
    _Float16* __restrict__ hpad,          // out h [B][66][66][64]
    float* __restrict__ cpix,             // in-place c [B][4096][64]
    const _Float16* __restrict__ wr,      // [NH*9(+1)][256][32]
    const float* __restrict__ bias,       // [256]
    const float* __restrict__ wh,         // [64]  (HEAD)
    const float* __restrict__ bh,         // [1]   (HEAD)
    float* __restrict__ outp,             // [B][64][64] (HEAD)
    _Float16* __restrict__ act,           // LDS, 2*ABUF halves (double buffer)
    _Float16* __restrict__ extra,         // LDS, 2560 halves: x-slab (XS) / head scratch
    int tid, int rb, int b)
{
    const int lane = tid & 63;
    const int n = lane & 15, q = lane >> 4;
    const int hg = tid >> 6;

    if (XS) {
        // x-slab staging at block start: B[k=tap][col], col=pix, k=sl*8+j (k>=9 zero)
        int pix = tid >> 2, sl = tid & 3;
        half8 hv;
        #pragma unroll
        for (int j = 0; j < 8; ++j) hv[j] = (_Float16)0.f;
        const float* xb = xsrc + b * (TSTEPS * HWSZ);
        if (sl == 0) {
            #pragma unroll
            for (int j = 0; j < 8; ++j) {
                int gy = rb - 1 + j / 3, gx = pix - 1 + j % 3;
                if (gy >= 0 && gy < IMH && gx >= 0 && gx < IMW)
                    hv[j] = (_Float16)xb[gy * IMW + gx];
            }
        } else if (sl == 1) {
            int gy = rb + 1, gx = pix + 1;               // tap 8: dy=2,dx=2
            if (gy < IMH && gx < IMW)
                hv[0] = (_Float16)xb[gy * IMW + gx];
        }
        *(half8*)&extra[(pix * 5 + sl) * 8] = hv;
    }

    floatx4 acc[4][4];
    #pragma unroll
    for (int g = 0; g < 4; ++g)
        #pragma unroll
        for (int i = 0; i < 4; ++i) acc[g][i] = (floatx4){0.f, 0.f, 0.f, 0.f};

    if (NH > 0) {
        stage_h(srcA, 0, act, tid, b, rb);   // chunk 0 -> buf 0
        __syncthreads();                     // buf0 (and extra, if XS) visible
    }

    #pragma unroll
    for (int chunk = 0; chunk < NH; ++chunk) {
        // Prefetch-stage chunk+1 into the OTHER buffer; overlaps with taps(chunk).
        if (chunk + 1 < NH)
            stage_h((chunk + 1 < 2) ? srcA : srcB, (chunk + 1) & 1,
                    act + ((chunk + 1) & 1) * ABUF, tid, b, rb);
        const _Float16* ab = act + (chunk & 1) * ABUF;
        const _Float16* wbase = wr + (chunk * 9) * 8192 + (hg * 16 + n) * 32 + q * 8;
        #pragma unroll
        for (int tap = 0; tap < 9; ++tap) {
            half8 wfr[4];
            #pragma unroll
            for (int g = 0; g < 4; ++g)
                wfr[g] = *(const half8*)(wbase + tap * 8192 + g * 2048);
            const int dy = tap / 3, dx = tap - dy * 3;
            half8 bfr[4];
            #pragma unroll
            for (int ni = 0; ni < 4; ++ni) {
                int col = 16 * ni + n + dx;
                bfr[ni] = *(const half8*)&ab[((dy * 66 + col) * 5 + q) * 8];
            }
            #pragma unroll
            for (int g = 0; g < 4; ++g)
                #pragma unroll
                for (int ni = 0; ni < 4; ++ni)
                    acc[g][ni] = __builtin_amdgcn_mfma_f32_16x16x32_f16(
                        wfr[g], bfr[ni], acc[g][ni], 0, 0, 0);
        }
        if (chunk + 1 < NH) __syncthreads();  // stage(chunk+1) visible; readers of
                                              // buf[(chunk+2)&1]'s target done
    }

    if (XS) {
        if (NH == 0) __syncthreads();        // only barrier needed when no chunks ran
        const _Float16* wbase = wr + (NH * 9) * 8192 + (hg * 16 + n) * 32 + q * 8;
        half8 wfr[4];
        #pragma unroll
        for (int g = 0; g < 4; ++g)
            wfr[g] = *(const half8*)(wbase + g * 2048);
        half8 bfr[4];
        #pragma unroll
        for (int ni = 0; ni < 4; ++ni)
            bfr[ni] = *(const half8*)&extra[((16 * ni + n) * 5 + q) * 8];
        #pragma unroll
        for (int g = 0; g < 4; ++g)
            #pragma unroll
            for (int ni = 0; ni < 4; ++ni)
                acc[g][ni] = __builtin_amdgcn_mfma_f32_16x16x32_f16(
                    wfr[g], bfr[ni], acc[g][ni], 0, 0, 0);
    }

    // Epilogue: lane holds gates for h = hg*16+q*4+r, pixel row rb, col 16*ni+n
    const int hb = hg * 16 + q * 4;
    floatx4 bi = *(const floatx4*)&bias[hb];
    floatx4 bf = *(const floatx4*)&bias[64 + hb];
    floatx4 bo = *(const floatx4*)&bias[128 + hb];
    floatx4 bg = *(const floatx4*)&bias[192 + hb];
    float* hd = (float*)extra;               // HEAD scratch: [64 col][17]
    float whv[4];
    if (HEAD) {
        #pragma unroll
        for (int r = 0; r < 4; ++r) whv[r] = wh[hb + r];
    }
    #pragma unroll
    for (int ni = 0; ni < 4; ++ni) {
        int col = 16 * ni + n;
        int cidx = ((b * HWSZ + rb * IMW + col) << 6) + hb;      // 32-bit offset
        floatx4 cold;
        if (CLOAD) cold = *(const floatx4*)(cpix + cidx);
        else       cold = (floatx4){0.f, 0.f, 0.f, 0.f};
        floatx4 cnew;
        half4 hv;
        #pragma unroll
        for (int r = 0; r < 4; ++r) {
            float zi = acc[0][ni][r] + bi[r];
            float zf = acc[1][ni][r] + bf[r];
            float zo = acc[2][ni][r] + bo[r];
            float zg = acc[3][ni][r] + bg[r];
            float cn = CLOAD ? fmaf(sigmoidf_(zf), cold[r], sigmoidf_(zi) * tanhf_(zg))
                             : sigmoidf_(zi) * tanhf_(zg);
            cnew[r] = cn;
            hv[r] = (_Float16)(sigmoidf_(zo) * tanhf_(cn));
        }
        if (HEAD) {
            // partial head sum over this lane's 4 hids (f16-rounded h, same numerics)
            float p = 0.f;
            #pragma unroll
            for (int r = 0; r < 4; ++r) p = fmaf((float)hv[r], whv[r], p);
            hd[col * 17 + (hg * 4 + q)] = p;
        } else {
            *(floatx4*)(cpix + cidx) = cnew;
            int hidx = (((b * PADW + rb + 1) * PADW + col + 1) << 6) + hb;
            *(half4*)(hpad + hidx) = hv;
        }
    }
    if (HEAD) {
        __syncthreads();
        if (tid < 64) {
            float s = bh[0];
            #pragma unroll
            for (int j = 0; j < 16; ++j) s += hd[tid * 17 + j];
            outp[b * HWSZ + rb * IMW + tid] = fmaxf(s, 0.f);
        }
    }
}

// ZMODE: 0 = role0 (L1) only, 1 = role1 (L0) only, 2 = both via blockIdx.z.
template<int NH1, bool C1, bool HEAD1, int NH0, bool XS0, bool C0, int ZMODE>
__global__ __launch_bounds__(256, 3) void fused_step(
    const _Float16* __restrict__ a1, const _Float16* __restrict__ b1,
    _Float16* __restrict__ h1o, float* __restrict__ c1p,
    const _Float16* __restrict__ w1r, const float* __restrict__ bias1,
    const _Float16* __restrict__ a0, const float* __restrict__ x0,
    _Float16* __restrict__ h0o, float* __restrict__ c0p,
    const _Float16* __restrict__ w0r, const float* __restrict__ bias0,
    const float* __restrict__ wh, const float* __restrict__ bh,
    float* __restrict__ outp)
{
    __shared__ __align__(16) _Float16 act[2 * ABUF];      // 31.7 KB (double buffer)
    __shared__ __align__(16) _Float16 extra[64 * 5 * 8];  // 5 KB: x-slab / head scratch
    const int tid = threadIdx.x;
    // XCD-aware row swizzle: one XCD handles a contiguous 8-row band.
    const int rb = ((blockIdx.x & 7) << 3) | (blockIdx.x >> 3);
    const int b = blockIdx.y;
    const int role = (ZMODE == 2) ? (int)blockIdx.z : ZMODE;
    if (ZMODE != 1 && role == 0)
        lstm_body<NH1, false, C1, HEAD1>(a1, b1, nullptr, h1o, c1p, w1r, bias1,
                                         wh, bh, outp, act, extra, tid, rb, b);
    else
        lstm_body<NH0, XS0, C0, false>(a0, nullptr, x0, h0o, c0p, w0r, bias0,
                                       nullptr, nullptr, nullptr, act, extra, tid, rb, b);
}

extern "C" void kernel_launch(void* const* d_in, const int* in_sizes, int n_in,
                              void* d_out, int out_size, void* d_ws, size_t ws_size,
                              hipStream_t stream) {
    const float* x  = (const float*)d_in[0];
    const float* w0 = (const float*)d_in[1];
    const float* b0 = (const float*)d_in[2];
    const float* w1 = (const float*)d_in[3];
    const float* b1 = (const float*)d_in[4];
    const float* wh = (const float*)d_in[5];
    const float* bh = (const float*)d_in[6];
    float* out = (float*)d_out;

    const size_t HPAD = (size_t)BATCH * PADW * PADW * 64;  // 4,460,544 halves
    const size_t CBUF = (size_t)BATCH * HWSZ * 64;         // 4,194,304 floats
    _Float16* hp  = (_Float16*)d_ws;
    _Float16* h0a = hp;
    _Float16* h0b = hp + HPAD;
    _Float16* h1a = hp + 2 * HPAD;
    _Float16* h1b = hp + 3 * HPAD;
    float* cbase = (float*)(hp + 4 * HPAD);
    float* c0 = cbase;
    float* c1 = cbase + CBUF;
    _Float16* wr0 = (_Float16*)(cbase + 2 * CBUF);   // 19*8192 halves
    _Float16* wr1 = wr0 + (size_t)19 * 8192;         // 36*8192 halves

    // Only h BORDERS need zeroing (interiors & c are written before read).
    border_zero<<<1040, 256, 0, stream>>>(hp);
    repack_w0<<<608, 256, 0, stream>>>(w0, wr0);
    repack_w1<<<1152, 256, 0, stream>>>(w1, wr1);

    _Float16* h0buf[2] = {h0a, h0b};
    _Float16* h1buf[2] = {h1a, h1b};
    dim3 block(256);

    // D0 = L0(0): h0(-1)=0 -> x-slab only (NH=0), c0(-1)=0 -> no c load.
    fused_step<0, false, false, 0, true, false, 1><<<dim3(64, BATCH, 1), block, 0, stream>>>(
        nullptr, nullptr, nullptr, nullptr, nullptr, nullptr,
        nullptr, x, h0buf[1], c0, wr0 + (size_t)18 * 8192, b0,
        nullptr, nullptr, nullptr);

    // D1 (t=1): role0 = L1(0): h1(-1)=0 -> NH=2, no c1 load; role1 = L0(1) full.
    fused_step<2, false, false, 2, true, true, 2><<<dim3(64, BATCH, 2), block, 0, stream>>>(
        h0buf[1], nullptr, h1buf[1], c1, wr1, b1,
        h0buf[1], x + (size_t)HWSZ, h0buf[0], c0, wr0, b0,
        nullptr, nullptr, nullptr);

    // steady t=2..15: role0 = L1(t-1) full; role1 = L0(t) full.
    for (int t = 2; t < TSTEPS; ++t) {
        fused_step<4, true, false, 2, true, true, 2><<<dim3(64, BATCH, 2), block, 0, stream>>>(
            h0buf[t & 1], h1buf[(t - 1) & 1], h1buf[t & 1], c1, wr1, b1,
            h0buf[t & 1], x + (size_t)t * HWSZ, h0buf[(t + 1) & 1], c0, wr0, b0,
            nullptr, nullptr, nullptr);
    }

    // final: L1(15) + fused head: writes ONLY the head output.
    fused_step<4, true, true, 0, false, false, 0><<<dim3(64, BATCH, 1), block, 0, stream>>>(
        h0buf[0], h1buf[1], nullptr, c1, wr1, b1,
        nullptr, nullptr, nullptr, nullptr, nullptr, nullptr,
        wh, bh, out);
}

// Round 21
// 1267.888 us; speedup vs baseline: 1.1489x; 1.0271x over previous
//
#include <hip/hip_runtime.h>

#define IMH 64
#define IMW 64
#define HWSZ 4096
#define BATCH 16
#define TSTEPS 16
#define PADW 66
#define ABUF 7920   // 198 px * 5 slots * 8 halves = one act buffer

typedef _Float16 half8 __attribute__((ext_vector_type(8)));
typedef _Float16 half4 __attribute__((ext_vector_type(4)));
typedef float floatx4 __attribute__((ext_vector_type(4)));
typedef int intx4 __attribute__((ext_vector_type(4)));

__device__ __forceinline__ float sigmoidf_(float x) { return 1.f / (1.f + __expf(-x)); }
__device__ __forceinline__ float tanhf_(float x) { return 1.f - 2.f / (1.f + __expf(2.f * x)); }

// layer1 weights: 36 slabs wr[gt][m][k32]; m=(g*4+hg)*16+i -> out=g*64+hg*16+i; ci=chunk*32+k.
__global__ void repack_w1(const float* __restrict__ w, _Float16* __restrict__ wr) {
    int total = 36 * 8192;
    for (int idx = blockIdx.x * blockDim.x + threadIdx.x; idx < total;
         idx += gridDim.x * blockDim.x) {
        int k = idx & 31;
        int m = (idx >> 5) & 255;
        int gt = idx >> 13;
        int chunk = gt / 9, tap = gt - chunk * 9;
        int g = m >> 6, hg = (m >> 4) & 3, i = m & 15;
        int out = g * 64 + hg * 16 + i;
        int ci = chunk * 32 + k;
        wr[idx] = (_Float16)w[(out * 128 + ci) * 9 + tap];
    }
}

// layer0 weights: 18 h-slabs (ci = chunk*32+k+1) + 1 x-slab (K-dim = tap: A[m][k]=w_x[out][k], k<9).
__global__ void repack_w0(const float* __restrict__ w, _Float16* __restrict__ wr) {
    int total = 19 * 8192;
    for (int idx = blockIdx.x * blockDim.x + threadIdx.x; idx < total;
         idx += gridDim.x * blockDim.x) {
        int k = idx & 31;
        int m = (idx >> 5) & 255;
        int gt = idx >> 13;
        int g = m >> 6, hg = (m >> 4) & 3, i = m & 15;
        int out = g * 64 + hg * 16 + i;
        float v = 0.f;
        if (gt < 18) {
            int chunk = gt / 9, tap = gt - chunk * 9;
            v = w[(out * 65 + (chunk * 32 + k + 1)) * 9 + tap];
        } else if (k < 9) {
            v = w[(out * 65 + 0) * 9 + k];   // x-plane, tap k
        }
        wr[idx] = (_Float16)v;
    }
}

// zero ONLY the halo border ring of the 4 contiguous h buffers.
__global__ void border_zero(_Float16* hp) {
    const int total = 4 * BATCH * 260 * 16;          // units of half4
    int idx = blockIdx.x * blockDim.x + threadIdx.x;
    if (idx >= total) return;
    int u = idx & 15;
    int t = idx >> 4;
    int e = t % 260; t /= 260;
    int b = t & 15;
    int buf = t >> 4;
    int py, px;
    if (e < 66)       { py = 0;       px = e; }
    else if (e < 132) { py = 65;      px = e - 66; }
    else if (e < 196) { py = e - 131; px = 0; }
    else              { py = e - 195; px = 65; }
    _Float16* p = hp + (size_t)buf * (BATCH * PADW * PADW * 64)
                + (((b * PADW + py) * PADW + px) << 6) + u * 4;
    *(half4*)p = (half4){(_Float16)0.f, (_Float16)0.f, (_Float16)0.f, (_Float16)0.f};
}

// ---- champion block structure: 256 thr = 4 waves = 4 hid-groups,
// ---- ONE image row x 64 cols, wave tile M=64 x N=64, __launch_bounds__(256,3)
// ---- (swept optimum). Act double-buffered, 1 barrier/chunk (R20).
// ---- R21: manual depth-2 software pipeline on the weight fragments — load
// ---- tap+1's wfr before tap's MFMAs so the vmem latency hides under them
// ---- (compiler settles at depth ~1 by heuristic even with budget; force it).

__device__ __forceinline__ void stage_h(const _Float16* __restrict__ buf, int halfsel,
                                        _Float16* __restrict__ dst, int tid, int b, int rb) {
    const int rowbase = (b * PADW + rb) * PADW;
    for (int t = tid; t < 792; t += 256) {
        int pix = t >> 2, sl = t & 3;
        int r = pix / 66, cs = pix - r * 66;
        int gofs = ((rowbase + r * PADW + cs) << 6) + (halfsel << 5) + (sl << 3);
        *(intx4*)&dst[(pix * 5 + sl) * 8] = *(const intx4*)(buf + gofs);
    }
}

// NH = # of 32-ch h chunks; XS = append x-slab; CLOAD = load previous c;
// HEAD = fuse 1x1-conv+ReLU head, skip h/c stores (final dispatch only).
template<int NH, bool XS, bool CLOAD, bool HEAD>
__device__ __forceinline__ void lstm_body(
    const _Float16* __restrict__ srcA,    // h chunks 0-1
    const _Float16* __restrict__ srcB,    // h chunks 2-3
    const float* __restrict__ xsrc,       // layer0 x_t
    _Float16* __restrict__ hpad,          // out h [B][66][66][64]
    float* __restrict__ cpix,             // in-place c [B][4096][64]
    const _Float16* __restrict__ wr,      // [NH*9(+1)][256][32]
    const float* __restrict__ bias,       // [256]
    const float* __restrict__ wh,         // [64]  (HEAD)
    const float* __restrict__ bh,         // [1]   (HEAD)
    float* __restrict__ outp,             // [B][64][64] (HEAD)
    _Float16* __restrict__ act,           // LDS, 2*ABUF halves (double buffer)
    _Float16* __restrict__ extra,         // LDS, 2560 halves: x-slab (XS) / head scratch
    int tid, int rb, int b)
{
    const int lane = tid & 63;
    const int n = lane & 15, q = lane >> 4;
    const int hg = tid >> 6;

    if (XS) {
        // x-slab staging at block start: B[k=tap][col], col=pix, k=sl*8+j (k>=9 zero)
        int pix = tid >> 2, sl = tid & 3;
        half8 hv;
        #pragma unroll
        for (int j = 0; j < 8; ++j) hv[j] = (_Float16)0.f;
        const float* xb = xsrc + b * (TSTEPS * HWSZ);
        if (sl == 0) {
            #pragma unroll
            for (int j = 0; j < 8; ++j) {
                int gy = rb - 1 + j / 3, gx = pix - 1 + j % 3;
                if (gy >= 0 && gy < IMH && gx >= 0 && gx < IMW)
                    hv[j] = (_Float16)xb[gy * IMW + gx];
            }
        } else if (sl == 1) {
            int gy = rb + 1, gx = pix + 1;               // tap 8: dy=2,dx=2
            if (gy < IMH && gx < IMW)
                hv[0] = (_Float16)xb[gy * IMW + gx];
        }
        *(half8*)&extra[(pix * 5 + sl) * 8] = hv;
    }

    floatx4 acc[4][4];
    #pragma unroll
    for (int g = 0; g < 4; ++g)
        #pragma unroll
        for (int i = 0; i < 4; ++i) acc[g][i] = (floatx4){0.f, 0.f, 0.f, 0.f};

    if (NH > 0) {
        stage_h(srcA, 0, act, tid, b, rb);   // chunk 0 -> buf 0
        __syncthreads();                     // buf0 (and extra, if XS) visible
    }

    #pragma unroll
    for (int chunk = 0; chunk < NH; ++chunk) {
        // Prefetch-stage chunk+1 into the OTHER buffer; overlaps with taps(chunk).
        if (chunk + 1 < NH)
            stage_h((chunk + 1 < 2) ? srcA : srcB, (chunk + 1) & 1,
                    act + ((chunk + 1) & 1) * ABUF, tid, b, rb);
        const _Float16* ab = act + (chunk & 1) * ABUF;
        const _Float16* wbase = wr + (chunk * 9) * 8192 + (hg * 16 + n) * 32 + q * 8;
        // depth-2 weight-fragment pipeline: wcur = tap, wnxt = tap+1 in flight
        half8 wcur[4];
        #pragma unroll
        for (int g = 0; g < 4; ++g)
            wcur[g] = *(const half8*)(wbase + g * 2048);
        #pragma unroll
        for (int tap = 0; tap < 9; ++tap) {
            half8 wnxt[4];
            if (tap + 1 < 9) {
                #pragma unroll
                for (int g = 0; g < 4; ++g)
                    wnxt[g] = *(const half8*)(wbase + (tap + 1) * 8192 + g * 2048);
            }
            const int dy = tap / 3, dx = tap - dy * 3;
            half8 bfr[4];
            #pragma unroll
            for (int ni = 0; ni < 4; ++ni) {
                int col = 16 * ni + n + dx;
                bfr[ni] = *(const half8*)&ab[((dy * 66 + col) * 5 + q) * 8];
            }
            #pragma unroll
            for (int g = 0; g < 4; ++g)
                #pragma unroll
                for (int ni = 0; ni < 4; ++ni)
                    acc[g][ni] = __builtin_amdgcn_mfma_f32_16x16x32_f16(
                        wcur[g], bfr[ni], acc[g][ni], 0, 0, 0);
            if (tap + 1 < 9) {
                #pragma unroll
                for (int g = 0; g < 4; ++g) wcur[g] = wnxt[g];
            }
        }
        if (chunk + 1 < NH) __syncthreads();  // stage(chunk+1) visible; readers of
                                              // buf[(chunk+2)&1]'s target done
    }

    if (XS) {
        if (NH == 0) __syncthreads();        // only barrier needed when no chunks ran
        const _Float16* wbase = wr + (NH * 9) * 8192 + (hg * 16 + n) * 32 + q * 8;
        half8 wfr[4];
        #pragma unroll
        for (int g = 0; g < 4; ++g)
            wfr[g] = *(const half8*)(wbase + g * 2048);
        half8 bfr[4];
        #pragma unroll
        for (int ni = 0; ni < 4; ++ni)
            bfr[ni] = *(const half8*)&extra[((16 * ni + n) * 5 + q) * 8];
        #pragma unroll
        for (int g = 0; g < 4; ++g)
            #pragma unroll
            for (int ni = 0; ni < 4; ++ni)
                acc[g][ni] = __builtin_amdgcn_mfma_f32_16x16x32_f16(
                    wfr[g], bfr[ni], acc[g][ni], 0, 0, 0);
    }

    // Epilogue: lane holds gates for h = hg*16+q*4+r, pixel row rb, col 16*ni+n
    const int hb = hg * 16 + q * 4;
    floatx4 bi = *(const floatx4*)&bias[hb];
    floatx4 bf = *(const floatx4*)&bias[64 + hb];
    floatx4 bo = *(const floatx4*)&bias[128 + hb];
    floatx4 bg = *(const floatx4*)&bias[192 + hb];
    float* hd = (float*)extra;               // HEAD scratch: [64 col][17]
    float whv[4];
    if (HEAD) {
        #pragma unroll
        for (int r = 0; r < 4; ++r) whv[r] = wh[hb + r];
    }
    #pragma unroll
    for (int ni = 0; ni < 4; ++ni) {
        int col = 16 * ni + n;
        int cidx = ((b * HWSZ + rb * IMW + col) << 6) + hb;      // 32-bit offset
        floatx4 cold;
        if (CLOAD) cold = *(const floatx4*)(cpix + cidx);
        else       cold = (floatx4){0.f, 0.f, 0.f, 0.f};
        floatx4 cnew;
        half4 hv;
        #pragma unroll
        for (int r = 0; r < 4; ++r) {
            float zi = acc[0][ni][r] + bi[r];
            float zf = acc[1][ni][r] + bf[r];
            float zo = acc[2][ni][r] + bo[r];
            float zg = acc[3][ni][r] + bg[r];
            float cn = CLOAD ? fmaf(sigmoidf_(zf), cold[r], sigmoidf_(zi) * tanhf_(zg))
                             : sigmoidf_(zi) * tanhf_(zg);
            cnew[r] = cn;
            hv[r] = (_Float16)(sigmoidf_(zo) * tanhf_(cn));
        }
        if (HEAD) {
            // partial head sum over this lane's 4 hids (f16-rounded h, same numerics)
            float p = 0.f;
            #pragma unroll
            for (int r = 0; r < 4; ++r) p = fmaf((float)hv[r], whv[r], p);
            hd[col * 17 + (hg * 4 + q)] = p;
        } else {
            *(floatx4*)(cpix + cidx) = cnew;
            int hidx = (((b * PADW + rb + 1) * PADW + col + 1) << 6) + hb;
            *(half4*)(hpad + hidx) = hv;
        }
    }
    if (HEAD) {
        __syncthreads();
        if (tid < 64) {
            float s = bh[0];
            #pragma unroll
            for (int j = 0; j < 16; ++j) s += hd[tid * 17 + j];
            outp[b * HWSZ + rb * IMW + tid] = fmaxf(s, 0.f);
        }
    }
}

// ZMODE: 0 = role0 (L1) only, 1 = role1 (L0) only, 2 = both via blockIdx.z.
template<int NH1, bool C1, bool HEAD1, int NH0, bool XS0, bool C0, int ZMODE>
__global__ __launch_bounds__(256, 3) void fused_step(
    const _Float16* __restrict__ a1, const _Float16* __restrict__ b1,
    _Float16* __restrict__ h1o, float* __restrict__ c1p,
    const _Float16* __restrict__ w1r, const float* __restrict__ bias1,
    const _Float16* __restrict__ a0, const float* __restrict__ x0,
    _Float16* __restrict__ h0o, float* __restrict__ c0p,
    const _Float16* __restrict__ w0r, const float* __restrict__ bias0,
    const float* __restrict__ wh, const float* __restrict__ bh,
    float* __restrict__ outp)
{
    __shared__ __align__(16) _Float16 act[2 * ABUF];      // 31.7 KB (double buffer)
    __shared__ __align__(16) _Float16 extra[64 * 5 * 8];  // 5 KB: x-slab / head scratch
    const int tid = threadIdx.x;
    // XCD-aware row swizzle: one XCD handles a contiguous 8-row band.
    const int rb = ((blockIdx.x & 7) << 3) | (blockIdx.x >> 3);
    const int b = blockIdx.y;
    const int role = (ZMODE == 2) ? (int)blockIdx.z : ZMODE;
    if (ZMODE != 1 && role == 0)
        lstm_body<NH1, false, C1, HEAD1>(a1, b1, nullptr, h1o, c1p, w1r, bias1,
                                         wh, bh, outp, act, extra, tid, rb, b);
    else
        lstm_body<NH0, XS0, C0, false>(a0, nullptr, x0, h0o, c0p, w0r, bias0,
                                       nullptr, nullptr, nullptr, act, extra, tid, rb, b);
}

extern "C" void kernel_launch(void* const* d_in, const int* in_sizes, int n_in,
                              void* d_out, int out_size, void* d_ws, size_t ws_size,
                              hipStream_t stream) {
    const float* x  = (const float*)d_in[0];
    const float* w0 = (const float*)d_in[1];
    const float* b0 = (const float*)d_in[2];
    const float* w1 = (const float*)d_in[3];
    const float* b1 = (const float*)d_in[4];
    const float* wh = (const float*)d_in[5];
    const float* bh = (const float*)d_in[6];
    float* out = (float*)d_out;

    const size_t HPAD = (size_t)BATCH * PADW * PADW * 64;  // 4,460,544 halves
    const size_t CBUF = (size_t)BATCH * HWSZ * 64;         // 4,194,304 floats
    _Float16* hp  = (_Float16*)d_ws;
    _Float16* h0a = hp;
    _Float16* h0b = hp + HPAD;
    _Float16* h1a = hp + 2 * HPAD;
    _Float16* h1b = hp + 3 * HPAD;
    float* cbase = (float*)(hp + 4 * HPAD);
    float* c0 = cbase;
    float* c1 = cbase + CBUF;
    _Float16* wr0 = (_Float16*)(cbase + 2 * CBUF);   // 19*8192 halves
    _Float16* wr1 = wr0 + (size_t)19 * 8192;         // 36*8192 halves

    // Only h BORDERS need zeroing (interiors & c are written before read).
    border_zero<<<1040, 256, 0, stream>>>(hp);
    repack_w0<<<608, 256, 0, stream>>>(w0, wr0);
    repack_w1<<<1152, 256, 0, stream>>>(w1, wr1);

    _Float16* h0buf[2] = {h0a, h0b};
    _Float16* h1buf[2] = {h1a, h1b};
    dim3 block(256);

    // D0 = L0(0): h0(-1)=0 -> x-slab only (NH=0), c0(-1)=0 -> no c load.
    fused_step<0, false, false, 0, true, false, 1><<<dim3(64, BATCH, 1), block, 0, stream>>>(
        nullptr, nullptr, nullptr, nullptr, nullptr, nullptr,
        nullptr, x, h0buf[1], c0, wr0 + (size_t)18 * 8192, b0,
        nullptr, nullptr, nullptr);

    // D1 (t=1): role0 = L1(0): h1(-1)=0 -> NH=2, no c1 load; role1 = L0(1) full.
    fused_step<2, false, false, 2, true, true, 2><<<dim3(64, BATCH, 2), block, 0, stream>>>(
        h0buf[1], nullptr, h1buf[1], c1, wr1, b1,
        h0buf[1], x + (size_t)HWSZ, h0buf[0], c0, wr0, b0,
        nullptr, nullptr, nullptr);

    // steady t=2..15: role0 = L1(t-1) full; role1 = L0(t) full.
    for (int t = 2; t < TSTEPS; ++t) {
        fused_step<4, true, false, 2, true, true, 2><<<dim3(64, BATCH, 2), block, 0, stream>>>(
            h0buf[t & 1], h1buf[(t - 1) & 1], h1buf[t & 1], c1, wr1, b1,
            h0buf[t & 1], x + (size_t)t * HWSZ, h0buf[(t + 1) & 1], c0, wr0, b0,
            nullptr, nullptr, nullptr);
    }

    // final: L1(15) + fused head: writes ONLY the head output.
    fused_step<4, true, true, 0, false, false, 0><<<dim3(64, BATCH, 1), block, 0, stream>>>(
        h0buf[0], h1buf[1], nullptr, c1, wr1, b1,
        nullptr, nullptr, nullptr, nullptr, nullptr, nullptr,
        wh, bh, out);
}